// Round 3
// baseline (152.754 us; speedup 1.0000x reference)
//
#include <hip/hip_runtime.h>
#include <math.h>

#define DEV static __device__ __forceinline__

constexpr int SS = 12;
constexpr int NN = 207;
constexpr int NCIRC = 64 * NN;          // 13248 circuits, 4 waves/block -> 3312 blocks

// Lane layout: amplitude index i = (lane<<2) | k, k=0..3.
// Amp bit 0,1 = "K slots" (in-lane); amp bit b>=2 = lane bit b-2 ("L slots").
// Initially qubit q sits at amp bit (7-q): q6->K1, q7->K0, q0..q5 -> L5..L0.
// Conv pairs are computed with BOTH qubits in K slots (pure register math);
// swap_kl<KB,J> exchanges K-bit KB with lane bit J (8 shfl_xor, static mask
// -> DPP/ds_swizzle lowering, NOT ds_bpermute: R2 showed bpermute costs 4.4M
// bank-conflict cycles and +45us).

struct St { float re[4]; float im[4]; };

template<int M>
DEV float sxc(float v) { return __shfl_xor(v, M, 64); }   // static mask

// RY on in-lane amplitude bit KB: pure FMAs.
template<int KB>
DEV void ry_k(St& st, float c, float s) {
    if constexpr (KB == 0) {
        float r0=st.re[0], r1=st.re[1], i0=st.im[0], i1=st.im[1];
        st.re[0] = fmaf(c, r0, -s*r1); st.re[1] = fmaf(s, r0, c*r1);
        st.im[0] = fmaf(c, i0, -s*i1); st.im[1] = fmaf(s, i0, c*i1);
        float r2=st.re[2], r3=st.re[3], i2=st.im[2], i3=st.im[3];
        st.re[2] = fmaf(c, r2, -s*r3); st.re[3] = fmaf(s, r2, c*r3);
        st.im[2] = fmaf(c, i2, -s*i3); st.im[3] = fmaf(s, i2, c*i3);
    } else {
        float r0=st.re[0], r2=st.re[2], i0=st.im[0], i2=st.im[2];
        st.re[0] = fmaf(c, r0, -s*r2); st.re[2] = fmaf(s, r0, c*r2);
        st.im[0] = fmaf(c, i0, -s*i2); st.im[2] = fmaf(s, i0, c*i2);
        float r1=st.re[1], r3=st.re[3], i1=st.im[1], i3=st.im[3];
        st.re[1] = fmaf(c, r1, -s*r3); st.re[3] = fmaf(s, r1, c*r3);
        st.im[1] = fmaf(c, i1, -s*i3); st.im[3] = fmaf(s, i1, c*i3);
    }
}

// CNOT with both control (bit CB) and target (bit TB) in-lane: register rename.
template<int CB, int TB>
DEV void cnot_kk(St& st) {
    if constexpr (CB == 1 && TB == 0) {
        float t = st.re[2]; st.re[2] = st.re[3]; st.re[3] = t;
        t = st.im[2]; st.im[2] = st.im[3]; st.im[3] = t;
    } else {  // CB==0, TB==1
        float t = st.re[1]; st.re[1] = st.re[3]; st.re[3] = t;
        t = st.im[1]; st.im[1] = st.im[3]; st.im[3] = t;
    }
}

// Swap in-lane amp bit KB with lane bit J (static shuffle mask 1<<J).
template<int KB, int J>
DEV void swap_kl(St& st) {
    constexpr int m = 1 << KB;
    const bool lb = (threadIdx.x >> J) & 1;
    float tr[4], ti[4];
#pragma unroll
    for (int k = 0; k < 4; k++) {
        tr[k] = sxc<(1 << J)>(st.re[k ^ m]);
        ti[k] = sxc<(1 << J)>(st.im[k ^ m]);
    }
#pragma unroll
    for (int k = 0; k < 4; k++) {
        const bool keep = ((((k >> KB) & 1) != 0) == lb);
        st.re[k] = keep ? st.re[k] : tr[k];
        st.im[k] = keep ? st.im[k] : ti[k];
    }
}

// RY on a lane-resident qubit at lane bit J (pool gates only).
template<int J>
DEV void ry_lane(St& st, float c, float s) {
    const float sg = ((threadIdx.x >> J) & 1) ? s : -s;
#pragma unroll
    for (int k = 0; k < 4; k++) {
        float pr = sxc<(1 << J)>(st.re[k]);
        float pi = sxc<(1 << J)>(st.im[k]);
        st.re[k] = fmaf(c, st.re[k], sg * pr);
        st.im[k] = fmaf(c, st.im[k], sg * pi);
    }
}

// Conv pair with qubit q1 at K-bit KA, qubit q2 at K-bit KB2. t8 = &tab[2*J].
template<int KA, int KB2>
DEV void conv_kk(St& st, const float* __restrict__ t8) {
    ry_k<KA>(st, t8[0], t8[1]);
    ry_k<KB2>(st, t8[2], t8[3]);
    cnot_kk<KA, KB2>(st);
    ry_k<KA>(st, t8[4], t8[5]);
    ry_k<KB2>(st, t8[6], t8[7]);
    cnot_kk<KB2, KA>(st);
}

// ---- pre-kernel: cos/sin table for the 64 q_params half-angles ----
__global__ void trig_kernel(const float* __restrict__ qp, float* __restrict__ tab) {
    int i = threadIdx.x;
    if (i < 64) {
        float s, c;
        sincosf(0.5f * qp[i], &s, &c);
        tab[2 * i]     = c;
        tab[2 * i + 1] = s;
    }
}

__global__ __launch_bounds__(256) void qcnn_kernel(
    const float* __restrict__ x, const float* __restrict__ adj,
    const float* __restrict__ w_proj, const float* __restrict__ b_proj,
    const float* __restrict__ tab,
    const float* __restrict__ w1, const float* __restrict__ b1,
    const float* __restrict__ w2, const float* __restrict__ b2,
    const float* __restrict__ w3, const float* __restrict__ b3,
    float* __restrict__ out)
{
    const int lane = threadIdx.x & 63;
    const int wv   = threadIdx.x >> 6;
    const int g    = blockIdx.x * 4 + wv;        // grid exact: 3312*4 == 13248
    const int b    = g / NN;
    const int node = g - b * NN;

    // ---- angles = x-slice @ w_proj.T + b_proj, clipped to [-pi, pi] ----
    float ang[8];
#pragma unroll
    for (int k = 0; k < 8; k++) ang[k] = b_proj[k];
    const float* xp = x + ((size_t)b * SS * NN + node) * 2;
#pragma unroll
    for (int s = 0; s < SS; s++) {
        const float2 xv = *(const float2*)(xp + (size_t)s * (NN * 2));
#pragma unroll
        for (int k = 0; k < 8; k++) {
            ang[k] = fmaf(xv.x, w_proj[k * 24 + 2 * s],     ang[k]);
            ang[k] = fmaf(xv.y, w_proj[k * 24 + 2 * s + 1], ang[k]);
        }
    }
    const float PI_F = 3.14159265358979323846f;
#pragma unroll
    for (int k = 0; k < 8; k++) ang[k] = fminf(fmaxf(ang[k], -PI_F), PI_F);

    // ---- product state after RY layer + RZ phases, built analytically ----
    float cc[8], ss[8];
#pragma unroll
    for (int i = 0; i < 8; i++) sincosf(0.5f * ang[i], &ss[i], &cc[i]);

    float A = 1.0f;
#pragma unroll
    for (int i = 0; i < 6; i++) {            // qubits 0..5 -> lane bits 5-i
        A *= ((threadIdx.x >> (5 - i)) & 1) ? ss[i] : cc[i];
    }
    float phi = 0.0f;
#pragma unroll
    for (int i = 0; i < 4; i++) {            // RZ on qubits 0..3 (lane bits 5..2)
        phi += ((threadIdx.x >> (5 - i)) & 1) ? 0.5f * ang[4 + i] : -0.5f * ang[4 + i];
    }
    float cp, sp;
    sincosf(phi, &sp, &cp);

    St st;
#pragma unroll
    for (int k = 0; k < 4; k++) {            // qubit6 -> k bit1, qubit7 -> k bit0
        float Ak = A * ((k & 2) ? ss[6] : cc[6]) * ((k & 1) ? ss[7] : cc[7]);
        st.re[k] = Ak * cp;
        st.im[k] = Ak * sp;
    }

    // ---- adjacency-controlled CNOT chain == single XOR-mask permutation ----
    const int c = node & 7;
    int M = 0;
#pragma unroll
    for (int t = 0; t < 8; t++) {
        float av = adj[c * NN + t];
        if (t != c && av > 0.0f) M |= 1 << (7 - t);
    }
    if (M) {
        const int Mlane = M >> 2;
        const int Mlo   = M & 3;
        float pr[4], pim[4];
#pragma unroll
        for (int k = 0; k < 4; k++) {        // runtime mask -> bpermute, once
            pr[k]  = __shfl_xor(st.re[k ^ Mlo], Mlane, 64);
            pim[k] = __shfl_xor(st.im[k ^ Mlo], Mlane, 64);
        }
        const int pc = 7 - c;                 // control amplitude bit
        if (pc >= 2) {
            const bool bb = (threadIdx.x >> (pc - 2)) & 1;
#pragma unroll
            for (int k = 0; k < 4; k++) {
                st.re[k] = bb ? pr[k]  : st.re[k];
                st.im[k] = bb ? pim[k] : st.im[k];
            }
        } else {
#pragma unroll
            for (int k = 0; k < 4; k++) {
                const bool bb = (k >> pc) & 1;
                st.re[k] = bb ? pr[k]  : st.re[k];
                st.im[k] = bb ? pim[k] : st.im[k];
            }
        }
    }

    // ---- conv layers with dynamic relayout (schedule verified in R2) ----
    // Slot map: K1,K0 | L5,L4,L3,L2,L1,L0 (values = qubit)
    //    init:  6,7 | 0,1,2,3,4,5
    conv_kk<1,0>(st, tab + 2*12);            // (6,7)
    swap_kl<1,1>(st);                        // 4,7 | 0,1,2,3,6,5
    swap_kl<0,0>(st);                        // 4,5 | 0,1,2,3,6,7
    conv_kk<1,0>(st, tab + 2*8);             // (4,5)
    swap_kl<1,1>(st);                        // 6,5 | 0,1,2,3,4,7
    conv_kk<0,1>(st, tab + 2*24);            // (5,6): q5=K0,q6=K1
    swap_kl<1,3>(st);                        // 2,5 | 0,1,6,3,4,7
    swap_kl<0,2>(st);                        // 2,3 | 0,1,6,5,4,7
    conv_kk<1,0>(st, tab + 2*4);             // (2,3)
    swap_kl<1,1>(st);                        // 4,3 | 0,1,6,5,2,7
    conv_kk<0,1>(st, tab + 2*20);            // (3,4): q3=K0,q4=K1
    swap_kl<1,5>(st);                        // 0,3 | 4,1,6,5,2,7
    swap_kl<0,4>(st);                        // 0,1 | 4,3,6,5,2,7
    conv_kk<1,0>(st, tab + 2*0);             // (0,1)
    swap_kl<1,1>(st);                        // 2,1 | 4,3,6,5,0,7
    conv_kk<0,1>(st, tab + 2*16);            // (1,2): q1=K0,q2=K1
    // ---- layer 2 ----
    swap_kl<0,4>(st);                        // 2,3 | 4,1,6,5,0,7
    conv_kk<1,0>(st, tab + 2*32);            // (2,3)
    swap_kl<1,1>(st);                        // 0,3 | 4,1,6,5,2,7
    swap_kl<0,4>(st);                        // 0,1 | 4,3,6,5,2,7
    conv_kk<1,0>(st, tab + 2*28);            // (0,1)
    swap_kl<1,1>(st);                        // 2,1 | 4,3,6,5,0,7
    conv_kk<0,1>(st, tab + 2*44);            // (1,2)
    swap_kl<1,5>(st);                        // 4,1 | 2,3,6,5,0,7
    swap_kl<0,2>(st);                        // 4,5 | 2,3,6,1,0,7
    conv_kk<1,0>(st, tab + 2*36);            // (4,5)
    swap_kl<0,4>(st);                        // 4,3 | 2,5,6,1,0,7
    conv_kk<0,1>(st, tab + 2*48);            // (3,4)
    swap_kl<1,3>(st);                        // 6,3 | 2,5,4,1,0,7
    swap_kl<0,0>(st);                        // 6,7 | 2,5,4,1,0,3
    conv_kk<1,0>(st, tab + 2*40);            // (6,7)
    swap_kl<0,4>(st);                        // 6,5 | 2,7,4,1,0,3
    conv_kk<0,1>(st, tab + 2*52);            // (5,6)
    // final layout: K1=q6, K0=q5 | L5=q2, L4=q7, L3=q4, L2=q1, L1=q0, L0=q3

    // ---- pool: RY on q0(L1), q2(L5), q4(L3), q6(K1) ----
    ry_lane<1>(st, tab[112], tab[113]);      // q0
    ry_lane<5>(st, tab[116], tab[117]);      // q2
    ry_lane<3>(st, tab[120], tab[121]);      // q4
    ry_k<1>(st, tab[124], tab[125]);         // q6

    // ---- z[q] from probabilities, per final layout ----
    float p0 = fmaf(st.re[0], st.re[0], st.im[0] * st.im[0]);
    float p1 = fmaf(st.re[1], st.re[1], st.im[1] * st.im[1]);
    float p2 = fmaf(st.re[2], st.re[2], st.im[2] * st.im[2]);
    float p3 = fmaf(st.re[3], st.re[3], st.im[3] * st.im[3]);
    float psum = (p0 + p1) + (p2 + p3);
    float zv[8];
    zv[6] = (p0 + p1) - (p2 + p3);           // K1 = q6
    zv[5] = (p0 - p1) + (p2 - p3);           // K0 = q5
    zv[2] = ((lane >> 5) & 1) ? -psum : psum;   // L5 = q2
    zv[7] = ((lane >> 4) & 1) ? -psum : psum;   // L4 = q7
    zv[4] = ((lane >> 3) & 1) ? -psum : psum;   // L3 = q4
    zv[1] = ((lane >> 2) & 1) ? -psum : psum;   // L2 = q1
    zv[0] = ((lane >> 1) & 1) ? -psum : psum;   // L1 = q0
    zv[3] = ((lane >> 0) & 1) ? -psum : psum;   // L0 = q3

    // butterfly reduce (static masks -> DPP/swizzle) -> full z in every lane
#pragma unroll
    for (int w = 0; w < 8; w++) zv[w] += sxc<1>(zv[w]);
#pragma unroll
    for (int w = 0; w < 8; w++) zv[w] += sxc<2>(zv[w]);
#pragma unroll
    for (int w = 0; w < 8; w++) zv[w] += sxc<4>(zv[w]);
#pragma unroll
    for (int w = 0; w < 8; w++) zv[w] += sxc<8>(zv[w]);
#pragma unroll
    for (int w = 0; w < 8; w++) zv[w] += sxc<16>(zv[w]);
#pragma unroll
    for (int w = 0; w < 8; w++) zv[w] += sxc<32>(zv[w]);

    // ---- MLP head: 8 -> 64 (relu) -> 32 (relu) -> 1 ----
    float h1 = b1[lane];
#pragma unroll
    for (int k = 0; k < 8; k++) h1 = fmaf(zv[k], w1[lane * 8 + k], h1);
    h1 = fmaxf(h1, 0.0f);

    __shared__ float h1s[4][64];
    h1s[wv][lane] = h1;
    __syncthreads();

    const int m = lane & 31;
    float h2 = b2[m];
#pragma unroll
    for (int j = 0; j < 64; j++) h2 = fmaf(h1s[wv][j], w2[m * 64 + j], h2);
    h2 = fmaxf(h2, 0.0f);

    float o = h2 * w3[m];
    o += sxc<1>(o);
    o += sxc<2>(o);
    o += sxc<4>(o);
    o += sxc<8>(o);
    o += sxc<16>(o);

    if (lane == 0) out[g] = o + b3[0];
}

extern "C" void kernel_launch(void* const* d_in, const int* in_sizes, int n_in,
                              void* d_out, int out_size, void* d_ws, size_t ws_size,
                              hipStream_t stream) {
    const float* x      = (const float*)d_in[0];
    const float* adj    = (const float*)d_in[1];
    const float* w_proj = (const float*)d_in[2];
    const float* b_proj = (const float*)d_in[3];
    const float* qp     = (const float*)d_in[4];
    const float* w1     = (const float*)d_in[5];
    const float* b1     = (const float*)d_in[6];
    const float* w2     = (const float*)d_in[7];
    const float* b2     = (const float*)d_in[8];
    const float* w3     = (const float*)d_in[9];
    const float* b3     = (const float*)d_in[10];
    float* out = (float*)d_out;
    float* tab = (float*)d_ws;                 // 128 floats

    hipLaunchKernelGGL(trig_kernel, dim3(1), dim3(64), 0, stream, qp, tab);
    hipLaunchKernelGGL(qcnn_kernel, dim3(NCIRC / 4), dim3(256), 0, stream,
                       x, adj, w_proj, b_proj, tab, w1, b1, w2, b2, w3, b3, out);
}

// Round 4
// 118.369 us; speedup vs baseline: 1.2905x; 1.2905x over previous
//
#include <hip/hip_runtime.h>
#include <math.h>

#define DEV static __device__ __forceinline__

constexpr int SS = 12;
constexpr int NN = 207;
constexpr int NCIRC = 64 * NN;          // 13248 circuits, 4 waves/block -> 3312 blocks

// Lane layout: amplitude index i = (lane<<2) | k, k=0..3.
// Amp bit 0,1 = "K slots" (in-lane, scalars r0..r3/i0..i3); amp bit b>=2 =
// lane bit b-2 ("L slots"). Initially qubit q sits at amp bit (7-q).
// Conv pairs run with BOTH qubits in K slots (pure register FMA);
// SWKL<KB,J> exchanges K-bit KB with lane bit J (8 static-mask shfl_xor).
//
// R2/R3 lesson: any runtime-indexed access into the state array defeats SROA
// -> PromoteAlloca pushes the 8-float state to LDS (8192B, 4.45M conflict
// cycles). State is therefore 8 NAMED SCALARS and the adjacency permutation
// is a wave-uniform static branch over the low mask bits.

template<int M> DEV float sxc(float v) { return __shfl_xor(v, M, 64); }

#define RY0(c, s) do { float _c=(c), _s=(s), _a;                         \
    _a=r0; r0=fmaf(_c,_a,-_s*r1); r1=fmaf(_s,_a,_c*r1);                  \
    _a=r2; r2=fmaf(_c,_a,-_s*r3); r3=fmaf(_s,_a,_c*r3);                  \
    _a=i0; i0=fmaf(_c,_a,-_s*i1); i1=fmaf(_s,_a,_c*i1);                  \
    _a=i2; i2=fmaf(_c,_a,-_s*i3); i3=fmaf(_s,_a,_c*i3); } while (0)

#define RY1(c, s) do { float _c=(c), _s=(s), _a;                         \
    _a=r0; r0=fmaf(_c,_a,-_s*r2); r2=fmaf(_s,_a,_c*r2);                  \
    _a=r1; r1=fmaf(_c,_a,-_s*r3); r3=fmaf(_s,_a,_c*r3);                  \
    _a=i0; i0=fmaf(_c,_a,-_s*i2); i2=fmaf(_s,_a,_c*i2);                  \
    _a=i1; i1=fmaf(_c,_a,-_s*i3); i3=fmaf(_s,_a,_c*i3); } while (0)

#define SWAP23 do { float _t=r2; r2=r3; r3=_t; _t=i2; i2=i3; i3=_t; } while (0)
#define SWAP13 do { float _t=r1; r1=r3; r3=_t; _t=i1; i1=i3; i3=_t; } while (0)

// conv pair: RY(a) q1; RY(b) q2; CNOT(q1->q2); RY(c) q1; RY(d) q2; CNOT(q2->q1)
#define CONV10(T) do { RY1((T)[0],(T)[1]); RY0((T)[2],(T)[3]); SWAP23;   \
                       RY1((T)[4],(T)[5]); RY0((T)[6],(T)[7]); SWAP13; } while (0)
#define CONV01(T) do { RY0((T)[0],(T)[1]); RY1((T)[2],(T)[3]); SWAP13;   \
                       RY0((T)[4],(T)[5]); RY1((T)[6],(T)[7]); SWAP23; } while (0)

// swap K-bit 1 with lane bit J
#define SWKL1(J) do { const bool _lb = (lane >> (J)) & 1;                \
    float _t0=sxc<(1<<(J))>(r2), _t1=sxc<(1<<(J))>(r3);                  \
    float _t2=sxc<(1<<(J))>(r0), _t3=sxc<(1<<(J))>(r1);                  \
    r0=_lb?_t0:r0; r1=_lb?_t1:r1; r2=_lb?r2:_t2; r3=_lb?r3:_t3;          \
    _t0=sxc<(1<<(J))>(i2); _t1=sxc<(1<<(J))>(i3);                        \
    _t2=sxc<(1<<(J))>(i0); _t3=sxc<(1<<(J))>(i1);                        \
    i0=_lb?_t0:i0; i1=_lb?_t1:i1; i2=_lb?i2:_t2; i3=_lb?i3:_t3; } while (0)

// swap K-bit 0 with lane bit J
#define SWKL0(J) do { const bool _lb = (lane >> (J)) & 1;                \
    float _t0=sxc<(1<<(J))>(r1), _t1=sxc<(1<<(J))>(r0);                  \
    float _t2=sxc<(1<<(J))>(r3), _t3=sxc<(1<<(J))>(r2);                  \
    r0=_lb?_t0:r0; r1=_lb?r1:_t1; r2=_lb?_t2:r2; r3=_lb?r3:_t3;          \
    _t0=sxc<(1<<(J))>(i1); _t1=sxc<(1<<(J))>(i0);                        \
    _t2=sxc<(1<<(J))>(i3); _t3=sxc<(1<<(J))>(i2);                        \
    i0=_lb?_t0:i0; i1=_lb?i1:_t1; i2=_lb?_t2:i2; i3=_lb?i3:_t3; } while (0)

// RY on lane-resident qubit at lane bit J (pool only)
#define RYL(J, c, s) do { float _c=(c), _s=(s);                          \
    const float _sg = ((lane >> (J)) & 1) ? _s : -_s;                    \
    float _p;                                                            \
    _p=sxc<(1<<(J))>(r0); r0=fmaf(_c,r0,_sg*_p);                         \
    _p=sxc<(1<<(J))>(r1); r1=fmaf(_c,r1,_sg*_p);                         \
    _p=sxc<(1<<(J))>(r2); r2=fmaf(_c,r2,_sg*_p);                         \
    _p=sxc<(1<<(J))>(r3); r3=fmaf(_c,r3,_sg*_p);                         \
    _p=sxc<(1<<(J))>(i0); i0=fmaf(_c,i0,_sg*_p);                         \
    _p=sxc<(1<<(J))>(i1); i1=fmaf(_c,i1,_sg*_p);                         \
    _p=sxc<(1<<(J))>(i2); i2=fmaf(_c,i2,_sg*_p);                         \
    _p=sxc<(1<<(J))>(i3); i3=fmaf(_c,i3,_sg*_p); } while (0)

// ---- pre-kernel: cos/sin table for the 64 q_params half-angles ----
__global__ void trig_kernel(const float* __restrict__ qp, float* __restrict__ tab) {
    int i = threadIdx.x;
    if (i < 64) {
        float s, c;
        sincosf(0.5f * qp[i], &s, &c);
        tab[2 * i]     = c;
        tab[2 * i + 1] = s;
    }
}

__global__ __launch_bounds__(256) void qcnn_kernel(
    const float* __restrict__ x, const float* __restrict__ adj,
    const float* __restrict__ w_proj, const float* __restrict__ b_proj,
    const float* __restrict__ tab,
    const float* __restrict__ w1, const float* __restrict__ b1,
    const float* __restrict__ w2, const float* __restrict__ b2,
    const float* __restrict__ w3, const float* __restrict__ b3,
    float* __restrict__ out)
{
    const int lane = threadIdx.x & 63;
    const int wv   = threadIdx.x >> 6;
    const int g    = blockIdx.x * 4 + wv;        // grid exact: 3312*4 == 13248
    const int b    = g / NN;
    const int node = g - b * NN;

    // ---- angles = x-slice @ w_proj.T + b_proj, clipped to [-pi, pi] ----
    float ang[8];
#pragma unroll
    for (int k = 0; k < 8; k++) ang[k] = b_proj[k];
    const float* xp = x + ((size_t)b * SS * NN + node) * 2;
#pragma unroll
    for (int s = 0; s < SS; s++) {
        const float2 xv = *(const float2*)(xp + (size_t)s * (NN * 2));
#pragma unroll
        for (int k = 0; k < 8; k++) {
            ang[k] = fmaf(xv.x, w_proj[k * 24 + 2 * s],     ang[k]);
            ang[k] = fmaf(xv.y, w_proj[k * 24 + 2 * s + 1], ang[k]);
        }
    }
    const float PI_F = 3.14159265358979323846f;
#pragma unroll
    for (int k = 0; k < 8; k++) ang[k] = fminf(fmaxf(ang[k], -PI_F), PI_F);

    // ---- product state after RY layer + RZ phases, built analytically ----
    float cc[8], ss[8];
#pragma unroll
    for (int i = 0; i < 8; i++) sincosf(0.5f * ang[i], &ss[i], &cc[i]);

    float A = 1.0f;
#pragma unroll
    for (int i = 0; i < 6; i++)              // qubits 0..5 -> lane bits 5-i
        A *= ((lane >> (5 - i)) & 1) ? ss[i] : cc[i];
    float phi = 0.0f;
#pragma unroll
    for (int i = 0; i < 4; i++)              // RZ on qubits 0..3 (lane bits 5..2)
        phi += ((lane >> (5 - i)) & 1) ? 0.5f * ang[4 + i] : -0.5f * ang[4 + i];
    float cp, sp;
    sincosf(phi, &sp, &cp);

    // state scalars: k index = in-lane amp bits (qubit6 -> bit1, qubit7 -> bit0)
    const float A0 = A * cc[6] * cc[7];
    const float A1 = A * cc[6] * ss[7];
    const float A2 = A * ss[6] * cc[7];
    const float A3 = A * ss[6] * ss[7];
    float r0 = A0 * cp, i0 = A0 * sp;
    float r1 = A1 * cp, i1 = A1 * sp;
    float r2 = A2 * cp, i2 = A2 * sp;
    float r3 = A3 * cp, i3 = A3 * sp;

    // ---- adjacency-controlled CNOT chain == single XOR-mask permutation ----
    // All of c, M, Mlane, Mlo, pc are wave-uniform -> uniform branches.
    const int c = node & 7;
    int M = 0;
#pragma unroll
    for (int t = 0; t < 8; t++) {
        float av = adj[c * NN + t];
        if (t != c && av > 0.0f) M |= 1 << (7 - t);
    }
    if (M) {
        const int Mlane = M >> 2;
        const int Mlo   = M & 3;
        float p0r, p1r, p2r, p3r, p0i, p1i, p2i, p3i;
        if (Mlo == 0) {
            p0r = __shfl_xor(r0, Mlane, 64); p1r = __shfl_xor(r1, Mlane, 64);
            p2r = __shfl_xor(r2, Mlane, 64); p3r = __shfl_xor(r3, Mlane, 64);
            p0i = __shfl_xor(i0, Mlane, 64); p1i = __shfl_xor(i1, Mlane, 64);
            p2i = __shfl_xor(i2, Mlane, 64); p3i = __shfl_xor(i3, Mlane, 64);
        } else if (Mlo == 1) {
            p0r = __shfl_xor(r1, Mlane, 64); p1r = __shfl_xor(r0, Mlane, 64);
            p2r = __shfl_xor(r3, Mlane, 64); p3r = __shfl_xor(r2, Mlane, 64);
            p0i = __shfl_xor(i1, Mlane, 64); p1i = __shfl_xor(i0, Mlane, 64);
            p2i = __shfl_xor(i3, Mlane, 64); p3i = __shfl_xor(i2, Mlane, 64);
        } else if (Mlo == 2) {
            p0r = __shfl_xor(r2, Mlane, 64); p1r = __shfl_xor(r3, Mlane, 64);
            p2r = __shfl_xor(r0, Mlane, 64); p3r = __shfl_xor(r1, Mlane, 64);
            p0i = __shfl_xor(i2, Mlane, 64); p1i = __shfl_xor(i3, Mlane, 64);
            p2i = __shfl_xor(i0, Mlane, 64); p3i = __shfl_xor(i1, Mlane, 64);
        } else {
            p0r = __shfl_xor(r3, Mlane, 64); p1r = __shfl_xor(r2, Mlane, 64);
            p2r = __shfl_xor(r1, Mlane, 64); p3r = __shfl_xor(r0, Mlane, 64);
            p0i = __shfl_xor(i3, Mlane, 64); p1i = __shfl_xor(i2, Mlane, 64);
            p2i = __shfl_xor(i1, Mlane, 64); p3i = __shfl_xor(i0, Mlane, 64);
        }
        const int pc = 7 - c;                 // control amplitude bit
        if (pc >= 2) {
            const bool bb = (lane >> (pc - 2)) & 1;
            r0 = bb ? p0r : r0; r1 = bb ? p1r : r1;
            r2 = bb ? p2r : r2; r3 = bb ? p3r : r3;
            i0 = bb ? p0i : i0; i1 = bb ? p1i : i1;
            i2 = bb ? p2i : i2; i3 = bb ? p3i : i3;
        } else if (pc == 1) {                 // k bit1 == 1 -> k = 2,3
            r2 = p2r; r3 = p3r; i2 = p2i; i3 = p3i;
        } else {                              // k bit0 == 1 -> k = 1,3
            r1 = p1r; r3 = p3r; i1 = p1i; i3 = p3i;
        }
    }

    // ---- conv layers with dynamic relayout (schedule verified R2/R3) ----
    // Slot map: K1,K0 | L5,L4,L3,L2,L1,L0 (values = qubit)
    //    init:  6,7 | 0,1,2,3,4,5
    CONV10(tab + 2*12);          // (6,7)
    SWKL1(1);                    // 4,7 | 0,1,2,3,6,5
    SWKL0(0);                    // 4,5 | 0,1,2,3,6,7
    CONV10(tab + 2*8);           // (4,5)
    SWKL1(1);                    // 6,5 | 0,1,2,3,4,7
    CONV01(tab + 2*24);          // (5,6): q5=K0,q6=K1
    SWKL1(3);                    // 2,5 | 0,1,6,3,4,7
    SWKL0(2);                    // 2,3 | 0,1,6,5,4,7
    CONV10(tab + 2*4);           // (2,3)
    SWKL1(1);                    // 4,3 | 0,1,6,5,2,7
    CONV01(tab + 2*20);          // (3,4): q3=K0,q4=K1
    SWKL1(5);                    // 0,3 | 4,1,6,5,2,7
    SWKL0(4);                    // 0,1 | 4,3,6,5,2,7
    CONV10(tab + 2*0);           // (0,1)
    SWKL1(1);                    // 2,1 | 4,3,6,5,0,7
    CONV01(tab + 2*16);          // (1,2): q1=K0,q2=K1
    // ---- layer 2 ----
    SWKL0(4);                    // 2,3 | 4,1,6,5,0,7
    CONV10(tab + 2*32);          // (2,3)
    SWKL1(1);                    // 0,3 | 4,1,6,5,2,7
    SWKL0(4);                    // 0,1 | 4,3,6,5,2,7
    CONV10(tab + 2*28);          // (0,1)
    SWKL1(1);                    // 2,1 | 4,3,6,5,0,7
    CONV01(tab + 2*44);          // (1,2)
    SWKL1(5);                    // 4,1 | 2,3,6,5,0,7
    SWKL0(2);                    // 4,5 | 2,3,6,1,0,7
    CONV10(tab + 2*36);          // (4,5)
    SWKL0(4);                    // 4,3 | 2,5,6,1,0,7
    CONV01(tab + 2*48);          // (3,4)
    SWKL1(3);                    // 6,3 | 2,5,4,1,0,7
    SWKL0(0);                    // 6,7 | 2,5,4,1,0,3
    CONV10(tab + 2*40);          // (6,7)
    SWKL0(4);                    // 6,5 | 2,7,4,1,0,3
    CONV01(tab + 2*52);          // (5,6)
    // final layout: K1=q6, K0=q5 | L5=q2, L4=q7, L3=q4, L2=q1, L1=q0, L0=q3

    // ---- pool: RY on q0(L1), q2(L5), q4(L3), q6(K1) ----
    RYL(1, tab[112], tab[113]);  // q0
    RYL(5, tab[116], tab[117]);  // q2
    RYL(3, tab[120], tab[121]);  // q4
    RY1(tab[124], tab[125]);     // q6

    // ---- z[q] from probabilities, per final layout ----
    float p0 = fmaf(r0, r0, i0 * i0);
    float p1 = fmaf(r1, r1, i1 * i1);
    float p2 = fmaf(r2, r2, i2 * i2);
    float p3 = fmaf(r3, r3, i3 * i3);
    float psum = (p0 + p1) + (p2 + p3);
    float zv[8];
    zv[6] = (p0 + p1) - (p2 + p3);           // K1 = q6
    zv[5] = (p0 - p1) + (p2 - p3);           // K0 = q5
    zv[2] = ((lane >> 5) & 1) ? -psum : psum;   // L5 = q2
    zv[7] = ((lane >> 4) & 1) ? -psum : psum;   // L4 = q7
    zv[4] = ((lane >> 3) & 1) ? -psum : psum;   // L3 = q4
    zv[1] = ((lane >> 2) & 1) ? -psum : psum;   // L2 = q1
    zv[0] = ((lane >> 1) & 1) ? -psum : psum;   // L1 = q0
    zv[3] = ((lane >> 0) & 1) ? -psum : psum;   // L0 = q3

    // butterfly reduce -> full z in every lane (static indices only)
#pragma unroll
    for (int w = 0; w < 8; w++) zv[w] += sxc<1>(zv[w]);
#pragma unroll
    for (int w = 0; w < 8; w++) zv[w] += sxc<2>(zv[w]);
#pragma unroll
    for (int w = 0; w < 8; w++) zv[w] += sxc<4>(zv[w]);
#pragma unroll
    for (int w = 0; w < 8; w++) zv[w] += sxc<8>(zv[w]);
#pragma unroll
    for (int w = 0; w < 8; w++) zv[w] += sxc<16>(zv[w]);
#pragma unroll
    for (int w = 0; w < 8; w++) zv[w] += sxc<32>(zv[w]);

    // ---- MLP head: 8 -> 64 (relu) -> 32 (relu) -> 1 ----
    float h1 = b1[lane];
#pragma unroll
    for (int k = 0; k < 8; k++) h1 = fmaf(zv[k], w1[lane * 8 + k], h1);
    h1 = fmaxf(h1, 0.0f);

    __shared__ float h1s[4][64];
    h1s[wv][lane] = h1;
    __syncthreads();

    const int m = lane & 31;
    float h2 = b2[m];
#pragma unroll
    for (int j = 0; j < 64; j++) h2 = fmaf(h1s[wv][j], w2[m * 64 + j], h2);
    h2 = fmaxf(h2, 0.0f);

    float o = h2 * w3[m];
    o += sxc<1>(o);
    o += sxc<2>(o);
    o += sxc<4>(o);
    o += sxc<8>(o);
    o += sxc<16>(o);

    if (lane == 0) out[g] = o + b3[0];
}

extern "C" void kernel_launch(void* const* d_in, const int* in_sizes, int n_in,
                              void* d_out, int out_size, void* d_ws, size_t ws_size,
                              hipStream_t stream) {
    const float* x      = (const float*)d_in[0];
    const float* adj    = (const float*)d_in[1];
    const float* w_proj = (const float*)d_in[2];
    const float* b_proj = (const float*)d_in[3];
    const float* qp     = (const float*)d_in[4];
    const float* w1     = (const float*)d_in[5];
    const float* b1     = (const float*)d_in[6];
    const float* w2     = (const float*)d_in[7];
    const float* b2     = (const float*)d_in[8];
    const float* w3     = (const float*)d_in[9];
    const float* b3     = (const float*)d_in[10];
    float* out = (float*)d_out;
    float* tab = (float*)d_ws;                 // 128 floats

    hipLaunchKernelGGL(trig_kernel, dim3(1), dim3(64), 0, stream, qp, tab);
    hipLaunchKernelGGL(qcnn_kernel, dim3(NCIRC / 4), dim3(256), 0, stream,
                       x, adj, w_proj, b_proj, tab, w1, b1, w2, b2, w3, b3, out);
}

// Round 5
// 114.983 us; speedup vs baseline: 1.3285x; 1.0294x over previous
//
#include <hip/hip_runtime.h>
#include <math.h>

#define DEV static __device__ __forceinline__

constexpr int SS = 12;
constexpr int NN = 207;
constexpr int NCIRC = 64 * NN;          // 13248 circuits, 4 waves/block -> 3312 blocks

// Lane layout: amplitude index i = (lane<<2) | k, k=0..3.
// Amp bits 0,1 = "K slots" (in-lane, named v2f scalars c0..c3 = (re,im));
// amp bit b>=2 = lane bit b-2 ("L slots"). Initially qubit q sits at amp bit
// (7-q). Each conv pair runs with BOTH qubits in K slots; since RY and CNOT
// are REAL matrices, the whole conv pair is ONE real 4x4 matrix, precomputed
// in prep_kernel (16 fma vs 64 for the gate sequence).
//
// Hard-won rules: (1) no runtime-indexed state arrays (SROA failure ->
// state demoted to LDS: R2/R3, 4.45M conflict cycles); (2) cross-lane moves
// use static-mask __shfl_xor (DPP/swizzle, conflict-free).

typedef float v2f __attribute__((ext_vector_type(2)));

DEV v2f splat2(float x) { v2f r; r.x = x; r.y = x; return r; }
DEV v2f vfma(float m, v2f a, v2f acc) { return __builtin_elementwise_fma(splat2(m), a, acc); }
DEV v2f vmul(float m, v2f a) { return splat2(m) * a; }
template<int M> DEV float sxc(float v) { return __shfl_xor(v, M, 64); }
template<int M> DEV v2f sx2(v2f v) { v2f r; r.x = sxc<M>(v.x); r.y = sxc<M>(v.y); return r; }

// Apply real 4x4 matrix P (row-major, uniform -> s_load) to (c0..c3).
#define CONVM(P) do {                                                     \
    v2f _a0 = c0, _a1 = c1, _a2 = c2, _a3 = c3;                           \
    c0 = vfma((P)[0],  _a0, vfma((P)[1],  _a1, vfma((P)[2],  _a2, vmul((P)[3],  _a3)))); \
    c1 = vfma((P)[4],  _a0, vfma((P)[5],  _a1, vfma((P)[6],  _a2, vmul((P)[7],  _a3)))); \
    c2 = vfma((P)[8],  _a0, vfma((P)[9],  _a1, vfma((P)[10], _a2, vmul((P)[11], _a3)))); \
    c3 = vfma((P)[12], _a0, vfma((P)[13], _a1, vfma((P)[14], _a2, vmul((P)[15], _a3)))); \
} while (0)

// Swap in-lane amp bit 1 with lane bit J.
#define SWKL1(J) do { const bool _lb = (lane >> (J)) & 1;                 \
    v2f _t0 = sx2<(1<<(J))>(c2), _t1 = sx2<(1<<(J))>(c3);                 \
    v2f _t2 = sx2<(1<<(J))>(c0), _t3 = sx2<(1<<(J))>(c1);                 \
    c0 = _lb ? _t0 : c0; c1 = _lb ? _t1 : c1;                             \
    c2 = _lb ? c2 : _t2; c3 = _lb ? c3 : _t3; } while (0)

// Swap in-lane amp bit 0 with lane bit J.
#define SWKL0(J) do { const bool _lb = (lane >> (J)) & 1;                 \
    v2f _t0 = sx2<(1<<(J))>(c1), _t1 = sx2<(1<<(J))>(c0);                 \
    v2f _t2 = sx2<(1<<(J))>(c3), _t3 = sx2<(1<<(J))>(c2);                 \
    c0 = _lb ? _t0 : c0; c1 = _lb ? c1 : _t1;                             \
    c2 = _lb ? _t2 : c2; c3 = _lb ? c3 : _t3; } while (0)

// RY on a lane-resident qubit at lane bit J (pool gates q0,q2,q4).
#define RYL(J, cc_, ss_) do { const float _c = (cc_), _s = (ss_);         \
    const float _sg = ((lane >> (J)) & 1) ? _s : -_s;                     \
    v2f _p;                                                               \
    _p = sx2<(1<<(J))>(c0); c0 = __builtin_elementwise_fma(splat2(_c), c0, vmul(_sg, _p)); \
    _p = sx2<(1<<(J))>(c1); c1 = __builtin_elementwise_fma(splat2(_c), c1, vmul(_sg, _p)); \
    _p = sx2<(1<<(J))>(c2); c2 = __builtin_elementwise_fma(splat2(_c), c2, vmul(_sg, _p)); \
    _p = sx2<(1<<(J))>(c3); c3 = __builtin_elementwise_fma(splat2(_c), c3, vmul(_sg, _p)); \
} while (0)

// ---- prep kernel: fuse each conv pair (RY,RY,CNOT,RY,RY,CNOT) into one ----
// ---- real 4x4 matrix in the main kernel's K-slot basis (k = 2*bK1 + bK0) --
// ws[16n..16n+15]: matrix for conv n (execution order); ws[224..229]: pool
// (c,s) for q0,q2,q4. Conv 13 has pool-RY(q6) premultiplied.
__global__ void prep_kernel(const float* __restrict__ qp, float* __restrict__ ws) {
    const int n = threadIdx.x;
    if (n == 14) {
        float s, c;
        sincosf(0.5f * qp[56], &s, &c); ws[224] = c; ws[225] = s;
        sincosf(0.5f * qp[58], &s, &c); ws[226] = c; ws[227] = s;
        sincosf(0.5f * qp[60], &s, &c); ws[228] = c; ws[229] = s;
    }
    if (n >= 14) return;
    // execution order: param offset J and variant V (0: q1@K1; 1: q1@K0)
    const int Jt[14] = {12, 8, 24, 4, 20, 0, 16, 32, 28, 44, 36, 48, 40, 52};
    const int Vt[14] = { 0, 0,  1, 0,  1, 0,  1,  0,  0,  1,  0,  1,  0,  1};
    const int J = Jt[n], v = Vt[n];
    float cg[4], sg[4];
    for (int i = 0; i < 4; i++) sincosf(0.5f * qp[J + i], &sg[i], &cg[i]);
    // hi slot (k bit1) holds q1 for V=0, q2 for V=1
    const int h1i = v ? 1 : 0, l1i = v ? 0 : 1;
    const int h2i = v ? 3 : 2, l2i = v ? 2 : 3;
    float A[16], B[16], M[16];
    {
        float H[2][2] = {{cg[h1i], -sg[h1i]}, {sg[h1i], cg[h1i]}};
        float L[2][2] = {{cg[l1i], -sg[l1i]}, {sg[l1i], cg[l1i]}};
        for (int a = 0; a < 2; a++) for (int b = 0; b < 2; b++)
            for (int p = 0; p < 2; p++) for (int q = 0; q < 2; q++)
                A[(2*a+b)*4 + (2*p+q)] = H[a][p] * L[b][q];
    }
    // first CNOT: V0 = ctrl hi,tgt lo -> swap rows 2,3; V1 = ctrl lo,tgt hi -> rows 1,3
    {
        const int ra = v ? 1 : 2;
        for (int j = 0; j < 4; j++) { float t = A[ra*4+j]; A[ra*4+j] = A[12+j]; A[12+j] = t; }
    }
    {
        float H[2][2] = {{cg[h2i], -sg[h2i]}, {sg[h2i], cg[h2i]}};
        float L[2][2] = {{cg[l2i], -sg[l2i]}, {sg[l2i], cg[l2i]}};
        for (int a = 0; a < 2; a++) for (int b = 0; b < 2; b++)
            for (int p = 0; p < 2; p++) for (int q = 0; q < 2; q++)
                B[(2*a+b)*4 + (2*p+q)] = H[a][p] * L[b][q];
    }
    for (int r = 0; r < 4; r++)
        for (int cl = 0; cl < 4; cl++) {
            float acc = 0.0f;
            for (int k = 0; k < 4; k++) acc += B[r*4+k] * A[k*4+cl];
            M[r*4+cl] = acc;
        }
    // second CNOT: V0 = ctrl lo,tgt hi -> swap rows 1,3; V1 = ctrl hi,tgt lo -> rows 2,3
    {
        const int rb = v ? 2 : 1;
        for (int j = 0; j < 4; j++) { float t = M[rb*4+j]; M[rb*4+j] = M[12+j]; M[12+j] = t; }
    }
    if (n == 13) {      // fold pool RY(q6) (q6 = hi slot of the last conv)
        float ps, pc;
        sincosf(0.5f * qp[62], &ps, &pc);
        for (int j = 0; j < 4; j++) {
            float r0 = M[j],     r2 = M[8+j];
            M[j]     = pc * r0 - ps * r2;
            M[8+j]   = ps * r0 + pc * r2;
            float r1 = M[4+j],   r3 = M[12+j];
            M[4+j]   = pc * r1 - ps * r3;
            M[12+j]  = ps * r1 + pc * r3;
        }
    }
    for (int i = 0; i < 16; i++) ws[16*n + i] = M[i];
}

__global__ __launch_bounds__(256) void qcnn_kernel(
    const float* __restrict__ x, const float* __restrict__ adj,
    const float* __restrict__ w_proj, const float* __restrict__ b_proj,
    const float* __restrict__ ws,
    const float* __restrict__ w1, const float* __restrict__ b1,
    const float* __restrict__ w2, const float* __restrict__ b2,
    const float* __restrict__ w3, const float* __restrict__ b3,
    float* __restrict__ out)
{
    const int lane = threadIdx.x & 63;
    const int wv   = threadIdx.x >> 6;
    const int g    = blockIdx.x * 4 + wv;        // grid exact: 3312*4 == 13248
    const int b    = g / NN;
    const int node = g - b * NN;

    // ---- angles = x-slice @ w_proj.T + b_proj, clipped to [-pi, pi] ----
    v2f av[8];
#pragma unroll
    for (int k = 0; k < 8; k++) av[k] = splat2(0.0f);
    const float* xp = x + ((size_t)b * SS * NN + node) * 2;
#pragma unroll
    for (int s = 0; s < SS; s++) {
        const v2f xv = *(const v2f*)(xp + (size_t)s * (NN * 2));
#pragma unroll
        for (int k = 0; k < 8; k++) {
            const v2f wv2 = *(const v2f*)(w_proj + k * 24 + 2 * s);
            av[k] = __builtin_elementwise_fma(xv, wv2, av[k]);
        }
    }
    const float PI_F = 3.14159265358979323846f;
    float ang[8];
#pragma unroll
    for (int k = 0; k < 8; k++)
        ang[k] = fminf(fmaxf(av[k].x + av[k].y + b_proj[k], -PI_F), PI_F);

    // ---- product state after RY layer + RZ phases, built analytically ----
    float cc[8], ss[8];
#pragma unroll
    for (int i = 0; i < 8; i++) __sincosf(0.5f * ang[i], &ss[i], &cc[i]);

    float A = 1.0f;
#pragma unroll
    for (int i = 0; i < 6; i++)              // qubits 0..5 -> lane bits 5-i
        A *= ((lane >> (5 - i)) & 1) ? ss[i] : cc[i];
    float phi = 0.0f;
#pragma unroll
    for (int i = 0; i < 4; i++)              // RZ on qubits 0..3 (lane bits 5..2)
        phi += ((lane >> (5 - i)) & 1) ? 0.5f * ang[4 + i] : -0.5f * ang[4 + i];
    float cp, sp;
    __sincosf(phi, &sp, &cp);

    // state: k = in-lane amp bits (qubit6 -> bit1, qubit7 -> bit0)
    v2f ph; ph.x = cp; ph.y = sp;
    v2f c0 = vmul(A * cc[6] * cc[7], ph);
    v2f c1 = vmul(A * cc[6] * ss[7], ph);
    v2f c2 = vmul(A * ss[6] * cc[7], ph);
    v2f c3 = vmul(A * ss[6] * ss[7], ph);

    // ---- adjacency-controlled CNOT chain == one XOR-mask permutation ----
    // cq, M, Mlane, Mlo, pc wave-uniform -> uniform branches.
    const int cq = node & 7;
    int M = 0;
#pragma unroll
    for (int t = 0; t < 8; t++) {
        float avv = adj[cq * NN + t];
        if (t != cq && avv > 0.0f) M |= 1 << (7 - t);
    }
    if (M) {
        const int Mlane = M >> 2;
        const int Mlo   = M & 3;
        v2f p0, p1, p2, p3;
        if (Mlo == 0)      { p0 = c0; p1 = c1; p2 = c2; p3 = c3; }
        else if (Mlo == 1) { p0 = c1; p1 = c0; p2 = c3; p3 = c2; }
        else if (Mlo == 2) { p0 = c2; p1 = c3; p2 = c0; p3 = c1; }
        else               { p0 = c3; p1 = c2; p2 = c1; p3 = c0; }
        p0.x = __shfl_xor(p0.x, Mlane, 64); p0.y = __shfl_xor(p0.y, Mlane, 64);
        p1.x = __shfl_xor(p1.x, Mlane, 64); p1.y = __shfl_xor(p1.y, Mlane, 64);
        p2.x = __shfl_xor(p2.x, Mlane, 64); p2.y = __shfl_xor(p2.y, Mlane, 64);
        p3.x = __shfl_xor(p3.x, Mlane, 64); p3.y = __shfl_xor(p3.y, Mlane, 64);
        const int pc = 7 - cq;                // control amplitude bit
        if (pc >= 2) {
            const bool bb = (lane >> (pc - 2)) & 1;
            c0 = bb ? p0 : c0; c1 = bb ? p1 : c1;
            c2 = bb ? p2 : c2; c3 = bb ? p3 : c3;
        } else if (pc == 1) {                 // k bit1 == 1 -> k = 2,3
            c2 = p2; c3 = p3;
        } else {                              // k bit0 == 1 -> k = 1,3
            c1 = p1; c3 = p3;
        }
    }

    // ---- conv layers: fused 4x4 matrices + relayout (schedule verified R4) --
    // Slot map: K1,K0 | L5,L4,L3,L2,L1,L0 (values = qubit); init: 6,7 | 0,1,2,3,4,5
    CONVM(ws + 0);               // (6,7)
    SWKL1(1);                    // 4,7 | 0,1,2,3,6,5
    SWKL0(0);                    // 4,5 | 0,1,2,3,6,7
    CONVM(ws + 16);              // (4,5)
    SWKL1(1);                    // 6,5 | 0,1,2,3,4,7
    CONVM(ws + 32);              // (5,6)
    SWKL1(3);                    // 2,5 | 0,1,6,3,4,7
    SWKL0(2);                    // 2,3 | 0,1,6,5,4,7
    CONVM(ws + 48);              // (2,3)
    SWKL1(1);                    // 4,3 | 0,1,6,5,2,7
    CONVM(ws + 64);              // (3,4)
    SWKL1(5);                    // 0,3 | 4,1,6,5,2,7
    SWKL0(4);                    // 0,1 | 4,3,6,5,2,7
    CONVM(ws + 80);              // (0,1)
    SWKL1(1);                    // 2,1 | 4,3,6,5,0,7
    CONVM(ws + 96);              // (1,2)
    // ---- layer 2 ----
    SWKL0(4);                    // 2,3 | 4,1,6,5,0,7
    CONVM(ws + 112);             // (2,3)
    SWKL1(1);                    // 0,3 | 4,1,6,5,2,7
    SWKL0(4);                    // 0,1 | 4,3,6,5,2,7
    CONVM(ws + 128);             // (0,1)
    SWKL1(1);                    // 2,1 | 4,3,6,5,0,7
    CONVM(ws + 144);             // (1,2)
    SWKL1(5);                    // 4,1 | 2,3,6,5,0,7
    SWKL0(2);                    // 4,5 | 2,3,6,1,0,7
    CONVM(ws + 160);             // (4,5)
    SWKL0(4);                    // 4,3 | 2,5,6,1,0,7
    CONVM(ws + 176);             // (3,4)
    SWKL1(3);                    // 6,3 | 2,5,4,1,0,7
    SWKL0(0);                    // 6,7 | 2,5,4,1,0,3
    CONVM(ws + 192);             // (6,7)
    SWKL0(4);                    // 6,5 | 2,7,4,1,0,3
    CONVM(ws + 208);             // (5,6) + pool RY(q6) folded in
    // final layout: K1=q6, K0=q5 | L5=q2, L4=q7, L3=q4, L2=q1, L1=q0, L0=q3

    // ---- pool: RY on q0(L1), q2(L5), q4(L3); q6 already folded ----
    RYL(1, ws[224], ws[225]);    // q0
    RYL(5, ws[226], ws[227]);    // q2
    RYL(3, ws[228], ws[229]);    // q4

    // ---- z[q] from probabilities, per final layout ----
    const float p0 = fmaf(c0.x, c0.x, c0.y * c0.y);
    const float p1 = fmaf(c1.x, c1.x, c1.y * c1.y);
    const float p2 = fmaf(c2.x, c2.x, c2.y * c2.y);
    const float p3 = fmaf(c3.x, c3.x, c3.y * c3.y);
    const float psum = (p0 + p1) + (p2 + p3);
    const float zK1 = (p0 + p1) - (p2 + p3);    // q6 (K1)
    const float zK0 = (p0 - p1) + (p2 - p3);    // q5 (K0)
    // pack z by qubit pairs: za=(q0,q1), zb=(q2,q3), zc=(q4,q5), zd=(q6,q7)
    v2f za, zb, zc, zd;
    za.x = ((lane >> 1) & 1) ? -psum : psum;    // q0 = L1
    za.y = ((lane >> 2) & 1) ? -psum : psum;    // q1 = L2
    zb.x = ((lane >> 5) & 1) ? -psum : psum;    // q2 = L5
    zb.y = (lane & 1)        ? -psum : psum;    // q3 = L0
    zc.x = ((lane >> 3) & 1) ? -psum : psum;    // q4 = L3
    zc.y = zK0;                                 // q5
    zd.x = zK1;                                 // q6
    zd.y = ((lane >> 4) & 1) ? -psum : psum;    // q7 = L4

    // butterfly reduce -> full z in every lane
#define BFLY(MM) do { za += sx2<MM>(za); zb += sx2<MM>(zb);               \
                      zc += sx2<MM>(zc); zd += sx2<MM>(zd); } while (0)
    BFLY(1); BFLY(2); BFLY(4); BFLY(8); BFLY(16); BFLY(32);
#undef BFLY

    // ---- MLP head: 8 -> 64 (relu) -> 32 (relu) -> 1 ----
    const v2f* w1v = (const v2f*)(w1 + lane * 8);
    v2f hv = za * w1v[0];
    hv = __builtin_elementwise_fma(zb, w1v[1], hv);
    hv = __builtin_elementwise_fma(zc, w1v[2], hv);
    hv = __builtin_elementwise_fma(zd, w1v[3], hv);
    const float h1 = fmaxf(b1[lane] + hv.x + hv.y, 0.0f);

    __shared__ float h1s[4][64];
    h1s[wv][lane] = h1;
    __syncthreads();

    const int m = lane & 31;
    const v2f* w2v = (const v2f*)(w2 + m * 64);
    const v2f* hsv = (const v2f*)(&h1s[wv][0]);
    v2f acc2 = splat2(0.0f);
#pragma unroll
    for (int j = 0; j < 32; j++)
        acc2 = __builtin_elementwise_fma(hsv[j], w2v[j], acc2);
    const float h2 = fmaxf(b2[m] + acc2.x + acc2.y, 0.0f);

    float o = h2 * w3[m];
    o += sxc<1>(o);
    o += sxc<2>(o);
    o += sxc<4>(o);
    o += sxc<8>(o);
    o += sxc<16>(o);

    if (lane == 0) out[g] = o + b3[0];
}

extern "C" void kernel_launch(void* const* d_in, const int* in_sizes, int n_in,
                              void* d_out, int out_size, void* d_ws, size_t ws_size,
                              hipStream_t stream) {
    const float* x      = (const float*)d_in[0];
    const float* adj    = (const float*)d_in[1];
    const float* w_proj = (const float*)d_in[2];
    const float* b_proj = (const float*)d_in[3];
    const float* qp     = (const float*)d_in[4];
    const float* w1     = (const float*)d_in[5];
    const float* b1     = (const float*)d_in[6];
    const float* w2     = (const float*)d_in[7];
    const float* b2     = (const float*)d_in[8];
    const float* w3     = (const float*)d_in[9];
    const float* b3     = (const float*)d_in[10];
    float* out = (float*)d_out;
    float* ws  = (float*)d_ws;                 // 230 floats

    hipLaunchKernelGGL(prep_kernel, dim3(1), dim3(64), 0, stream, qp, ws);
    hipLaunchKernelGGL(qcnn_kernel, dim3(NCIRC / 4), dim3(256), 0, stream,
                       x, adj, w_proj, b_proj, ws, w1, b1, w2, b2, w3, b3, out);
}